// Round 15
// baseline (45.212 us; speedup 1.0000x reference)
//
#include <hip/hip_runtime.h>
#include <hip/hip_bf16.h>
#include <utility>

#define LOG2E 1.4426950408889634f

#if __has_builtin(__builtin_amdgcn_exp2f)
#define EXP2F(x) __builtin_amdgcn_exp2f(x)
#else
#define EXP2F(x) exp2f(x)
#endif

#if __has_builtin(__builtin_amdgcn_rsqf)
#define RSQ(x) __builtin_amdgcn_rsqf(x)
#else
#define RSQ(x) (1.0f / sqrtf(x))
#endif

// readlane: lane may be a literal OR a runtime-uniform (SGPR) value.
#define RDLANE(x, l) __int_as_float(__builtin_amdgcn_readlane(__float_as_int(x), (l)))

// ---------------------------------------------------------------------------
// Kernel 1 (byte-identical to R9): rolled-outer / padded-unrolled-inner
// Cholesky, one wave. R9 evidence: dropped out of rocprof top-5.
// ---------------------------------------------------------------------------
typedef float f16v __attribute__((ext_vector_type(16)));
struct Rows { f16v v0, v1, v2, v3; };

template<int J> __device__ __forceinline__ float getR(const Rows& r) {
    if constexpr (J < 16)      return r.v0[J];
    else if constexpr (J < 32) return r.v1[J - 16];
    else if constexpr (J < 48) return r.v2[J - 32];
    else                       return r.v3[J - 48];
}
template<int J> __device__ __forceinline__ void setR(Rows& r, float x) {
    if constexpr (J < 16)      r.v0[J] = x;
    else if constexpr (J < 32) r.v1[J - 16] = x;
    else if constexpr (J < 48) r.v2[J - 32] = x;
    else                       r.v3[J - 48] = x;
}

template<int LO, int W>
__device__ __forceinline__ float selR(const Rows& r, int k) {
    if constexpr (W == 1) {
        return getR<LO>(r);
    } else {
        float lo = selR<LO, W / 2>(r, k);
        float hi = selR<LO + W / 2, W / 2>(r, k);
        return (k & (W / 2)) ? hi : lo;   // uniform cond -> cndmask, CSE'd
    }
}

template<int J>
__device__ __forceinline__ void upd1(Rows& r, float lk) {
    float ljk = RDLANE(lk, J);                 // literal source lane
    setR<J>(r, fmaf(-lk, ljk, getR<J>(r)));
}
template<int LO, int... Js>
__device__ __forceinline__ void upd_seq(Rows& r, float lk,
                                        std::integer_sequence<int, Js...>) {
    (upd1<LO + Js>(r, lk), ...);
}

template<int... Js>
__device__ __forceinline__ void load_row(Rows& r, const float* Lrow,
                                         std::integer_sequence<int, Js...>) {
    (setR<Js>(r, Lrow[Js]), ...);
}

template<int KLO, int KHI, int ULO>
__device__ __forceinline__ void chol_phase(Rows& r, float* Lsh, int lane) {
#pragma clang loop unroll(disable)
    for (int k = KLO; k < KHI; ++k) {
        float rk  = selR<ULO, 64 - ULO>(r, k); // A[l][k] (valid l >= k)
        float dk  = RDLANE(rk, k);             // A[k][k], uniform
        float inv = RSQ(dk);                   // 1/L[k][k]
        float lk  = rk * inv;                  // L[l][k]
        float st  = (lane == k) ? inv : lk;    // diag slot stores reciprocal
        Lsh[lane * 65 + k] = st;               // sink column k (conflict-free)
        upd_seq<ULO>(r, lk, std::make_integer_sequence<int, 64 - ULO>{});
    }
}

__global__ __launch_bounds__(64, 1)
void gp_precompute(const float* __restrict__ Z, const float* __restrict__ U,
                   const float* __restrict__ sf_p, const float* __restrict__ ell_p,
                   float* __restrict__ ws) {
    __shared__ float Lsh[64 * 65];
    const int lane = threadIdx.x;          // 64 threads = 1 wave
    const float sf  = sf_p[0];
    const float ell = ell_p[0];
    const float inv_ell = 1.0f / ell;
    const float sf2 = sf * sf;

    const float z0 = Z[lane * 3 + 0] * inv_ell;
    const float z1 = Z[lane * 3 + 1] * inv_ell;
    const float z2 = Z[lane * 3 + 2] * inv_ell;

#pragma clang loop unroll(disable)
    for (int j = 0; j < 64; ++j) {
        float dx = z0 - RDLANE(z0, j);
        float dy = z1 - RDLANE(z1, j);
        float dz = z2 - RDLANE(z2, j);
        float sq = dx * dx + dy * dy + dz * dz;
        Lsh[lane * 65 + j] = sf2 * EXP2F(-0.5f * LOG2E * sq);
    }
    __syncthreads();

    Rows r;
    load_row(r, &Lsh[lane * 65], std::make_integer_sequence<int, 64>{});

    chol_phase< 0, 32,  0>(r, Lsh, lane);
    chol_phase<32, 48, 32>(r, Lsh, lane);
    chol_phase<48, 64, 48>(r, Lsh, lane);
    __syncthreads();

    float s0 = U[lane * 2 + 0];
    float s1 = U[lane * 2 + 1];
    float w0v = 0.0f, w1v = 0.0f;
#pragma unroll 8
    for (int i = 63; i >= 0; --i) {
        float a   = Lsh[i * 65 + lane];    // L[i][lane]; lane i: 1/L[i][i]
        float rdi = RDLANE(a, i);          // 1/L[i][i]
        float w0  = RDLANE(s0, i) * rdi;   // W[i][0]
        float w1  = RDLANE(s1, i) * rdi;   // W[i][1]
        bool  me  = (lane == i);
        w0v = me ? w0 : w0v;
        w1v = me ? w1 : w1v;
        s0 = fmaf(-a, w0, s0);             // lanes >= i polluted after use
        s1 = fmaf(-a, w1, s1);
    }

    const float dm = -0.5f * LOG2E * (z0 * z0 + z1 * z1 + z2 * z2);
    float4* ws4 = (float4*)ws;
    ws4[lane * 2 + 0] = make_float4(z0, z1, z2, dm);
    ws4[lane * 2 + 1] = make_float4(sf2 * w0v, sf2 * w1v, 0.0f, 0.0f);
}

// ---------------------------------------------------------------------------
// Kernel 2, R15: minimize LDS-pipe cycles (the forward's critical resource).
// Accounting: per wave the m-loop issues the broadcast P reads; total LDS
// cycles/CU = waves/CU x instrs x cyc. Fixes vs R14:
//  - 4 pts/thread (977 blocks): halves wave count -> halves LDS instr total
//  - P split into float4[64] (b128, 12cyc) + float2[64] (b64, ~6cyc): 18 vs
//    24 cyc per m
//  - X loads: 3x float4 per thread (12 consecutive floats, 48t bytes is
//    16B-aligned); out: 2x float4 stores
//  - unroll 4 (R13 showed full unroll -> VGPR 200 -> occupancy collapse)
// ---------------------------------------------------------------------------
__global__ __launch_bounds__(256) void gp_forward(const float* __restrict__ X,
                                                  const float* __restrict__ ws,
                                                  const float* __restrict__ ell_p,
                                                  float* __restrict__ out, int n) {
    __shared__ float4 P4[64];   // {zs0, zs1, zs2, dm}
    __shared__ float2 P2[64];   // {w0, w1}
    for (int i = threadIdx.x; i < 64; i += 256) {
        float4 a = ((const float4*)ws)[2 * i + 0];
        float4 b = ((const float4*)ws)[2 * i + 1];
        P4[i] = a;
        P2[i] = make_float2(b.x, b.y);
    }
    const float inv_ell = 1.0f / ell_p[0];
    __syncthreads();

    const int t  = blockIdx.x * 256 + threadIdx.x;  // global thread id
    const int i0 = 4 * t;                            // first of 4 points

    float px[4], py[4], pz[4];
    if (i0 + 3 < n) {
        const float4* X4 = (const float4*)X;         // 12 floats = 3 float4
        float4 xa = X4[3 * t + 0];
        float4 xb = X4[3 * t + 1];
        float4 xc = X4[3 * t + 2];
        px[0] = xa.x; py[0] = xa.y; pz[0] = xa.z;
        px[1] = xa.w; py[1] = xb.x; pz[1] = xb.y;
        px[2] = xb.z; py[2] = xb.w; pz[2] = xc.x;
        px[3] = xc.y; py[3] = xc.z; pz[3] = xc.w;
    } else {
#pragma unroll
        for (int p = 0; p < 4; ++p) {
            int i = i0 + p;
            int ii = (i < n) ? i : (n - 1);
            px[p] = X[3 * ii + 0]; py[p] = X[3 * ii + 1]; pz[p] = X[3 * ii + 2];
        }
    }

    float xt0[4], xt1[4], xt2[4], c[4];
#pragma unroll
    for (int p = 0; p < 4; ++p) {
        float xs0 = px[p] * inv_ell;
        float xs1 = py[p] * inv_ell;
        float xs2 = pz[p] * inv_ell;
        c[p]  = -0.5f * LOG2E * (xs0 * xs0 + xs1 * xs1 + xs2 * xs2);
        xt0[p] = xs0 * LOG2E;
        xt1[p] = xs1 * LOG2E;
        xt2[p] = xs2 * LOG2E;
    }

    float acc0[4] = {0.f, 0.f, 0.f, 0.f};
    float acc1[4] = {0.f, 0.f, 0.f, 0.f};

#pragma unroll 4
    for (int m = 0; m < 64; ++m) {
        const float4 a = P4[m];             // ds_read_b128 (broadcast)
        const float2 b = P2[m];             // ds_read_b64  (broadcast)
#pragma unroll
        for (int p = 0; p < 4; ++p) {
            float arg = fmaf(xt0[p], a.x,
                        fmaf(xt1[p], a.y,
                        fmaf(xt2[p], a.z, c[p] + a.w)));
            float e = EXP2F(arg);
            acc0[p] = fmaf(e, b.x, acc0[p]);
            acc1[p] = fmaf(e, b.y, acc1[p]);
        }
    }

    if (i0 + 3 < n) {
        float4* out4 = (float4*)out;                 // 8 floats = 2 float4
        out4[2 * t + 0] = make_float4(acc0[0], acc1[0], acc0[1], acc1[1]);
        out4[2 * t + 1] = make_float4(acc0[2], acc1[2], acc0[3], acc1[3]);
    } else {
#pragma unroll
        for (int p = 0; p < 4; ++p) {
            int i = i0 + p;
            if (i < n) ((float2*)out)[i] = make_float2(acc0[p], acc1[p]);
        }
    }
}

extern "C" void kernel_launch(void* const* d_in, const int* in_sizes, int n_in,
                              void* d_out, int out_size, void* d_ws, size_t ws_size,
                              hipStream_t stream) {
    // setup_inputs order: t, X, Z, U, sf, ell
    const float* X    = (const float*)d_in[1];
    const float* Z    = (const float*)d_in[2];
    const float* U    = (const float*)d_in[3];
    const float* sf   = (const float*)d_in[4];
    const float* ell  = (const float*)d_in[5];
    float* out = (float*)d_out;
    float* ws  = (float*)d_ws;
    const int N = in_sizes[1] / 3;

    gp_precompute<<<1, 64, 0, stream>>>(Z, U, sf, ell, ws);

    const int PTS_PER_BLOCK = 256 * 4;      // 4 points per thread
    const int blocks = (N + PTS_PER_BLOCK - 1) / PTS_PER_BLOCK;
    gp_forward<<<blocks, 256, 0, stream>>>(X, ws, ell, out, N);
}

// Round 16
// 43.860 us; speedup vs baseline: 1.0308x; 1.0308x over previous
//
#include <hip/hip_runtime.h>
#include <hip/hip_bf16.h>
#include <utility>

#define LOG2E 1.4426950408889634f

#if __has_builtin(__builtin_amdgcn_exp2f)
#define EXP2F(x) __builtin_amdgcn_exp2f(x)
#else
#define EXP2F(x) exp2f(x)
#endif

#if __has_builtin(__builtin_amdgcn_rsqf)
#define RSQ(x) __builtin_amdgcn_rsqf(x)
#else
#define RSQ(x) (1.0f / sqrtf(x))
#endif

// readlane: lane may be a literal OR a runtime-uniform (SGPR) value.
#define RDLANE(x, l) __int_as_float(__builtin_amdgcn_readlane(__float_as_int(x), (l)))

// ---------------------------------------------------------------------------
// Kernel 1 (R9 structure; only the final ws store changed to the packed
// 6-float layout): rolled-outer / padded-unrolled-inner Cholesky, one wave.
// ---------------------------------------------------------------------------
typedef float f16v __attribute__((ext_vector_type(16)));
struct Rows { f16v v0, v1, v2, v3; };

template<int J> __device__ __forceinline__ float getR(const Rows& r) {
    if constexpr (J < 16)      return r.v0[J];
    else if constexpr (J < 32) return r.v1[J - 16];
    else if constexpr (J < 48) return r.v2[J - 32];
    else                       return r.v3[J - 48];
}
template<int J> __device__ __forceinline__ void setR(Rows& r, float x) {
    if constexpr (J < 16)      r.v0[J] = x;
    else if constexpr (J < 32) r.v1[J - 16] = x;
    else if constexpr (J < 48) r.v2[J - 32] = x;
    else                       r.v3[J - 48] = x;
}

template<int LO, int W>
__device__ __forceinline__ float selR(const Rows& r, int k) {
    if constexpr (W == 1) {
        return getR<LO>(r);
    } else {
        float lo = selR<LO, W / 2>(r, k);
        float hi = selR<LO + W / 2, W / 2>(r, k);
        return (k & (W / 2)) ? hi : lo;   // uniform cond -> cndmask, CSE'd
    }
}

template<int J>
__device__ __forceinline__ void upd1(Rows& r, float lk) {
    float ljk = RDLANE(lk, J);                 // literal source lane
    setR<J>(r, fmaf(-lk, ljk, getR<J>(r)));
}
template<int LO, int... Js>
__device__ __forceinline__ void upd_seq(Rows& r, float lk,
                                        std::integer_sequence<int, Js...>) {
    (upd1<LO + Js>(r, lk), ...);
}

template<int... Js>
__device__ __forceinline__ void load_row(Rows& r, const float* Lrow,
                                         std::integer_sequence<int, Js...>) {
    (setR<Js>(r, Lrow[Js]), ...);
}

template<int KLO, int KHI, int ULO>
__device__ __forceinline__ void chol_phase(Rows& r, float* Lsh, int lane) {
#pragma clang loop unroll(disable)
    for (int k = KLO; k < KHI; ++k) {
        float rk  = selR<ULO, 64 - ULO>(r, k); // A[l][k] (valid l >= k)
        float dk  = RDLANE(rk, k);             // A[k][k], uniform
        float inv = RSQ(dk);                   // 1/L[k][k]
        float lk  = rk * inv;                  // L[l][k]
        float st  = (lane == k) ? inv : lk;    // diag slot stores reciprocal
        Lsh[lane * 65 + k] = st;               // sink column k (conflict-free)
        upd_seq<ULO>(r, lk, std::make_integer_sequence<int, 64 - ULO>{});
    }
}

__global__ __launch_bounds__(64, 1)
void gp_precompute(const float* __restrict__ Z, const float* __restrict__ U,
                   const float* __restrict__ sf_p, const float* __restrict__ ell_p,
                   float* __restrict__ ws) {
    __shared__ float Lsh[64 * 65];
    const int lane = threadIdx.x;          // 64 threads = 1 wave
    const float sf  = sf_p[0];
    const float ell = ell_p[0];
    const float inv_ell = 1.0f / ell;
    const float sf2 = sf * sf;

    const float z0 = Z[lane * 3 + 0] * inv_ell;
    const float z1 = Z[lane * 3 + 1] * inv_ell;
    const float z2 = Z[lane * 3 + 2] * inv_ell;

#pragma clang loop unroll(disable)
    for (int j = 0; j < 64; ++j) {
        float dx = z0 - RDLANE(z0, j);
        float dy = z1 - RDLANE(z1, j);
        float dz = z2 - RDLANE(z2, j);
        float sq = dx * dx + dy * dy + dz * dz;
        Lsh[lane * 65 + j] = sf2 * EXP2F(-0.5f * LOG2E * sq);
    }
    __syncthreads();

    Rows r;
    load_row(r, &Lsh[lane * 65], std::make_integer_sequence<int, 64>{});

    chol_phase< 0, 32,  0>(r, Lsh, lane);
    chol_phase<32, 48, 32>(r, Lsh, lane);
    chol_phase<48, 64, 48>(r, Lsh, lane);
    __syncthreads();

    float s0 = U[lane * 2 + 0];
    float s1 = U[lane * 2 + 1];
    float w0v = 0.0f, w1v = 0.0f;
#pragma unroll 8
    for (int i = 63; i >= 0; --i) {
        float a   = Lsh[i * 65 + lane];    // L[i][lane]; lane i: 1/L[i][i]
        float rdi = RDLANE(a, i);          // 1/L[i][i]
        float w0  = RDLANE(s0, i) * rdi;   // W[i][0]
        float w1  = RDLANE(s1, i) * rdi;   // W[i][1]
        bool  me  = (lane == i);
        w0v = me ? w0 : w0v;
        w1v = me ? w1 : w1v;
        s0 = fmaf(-a, w0, s0);             // lanes >= i polluted after use
        s1 = fmaf(-a, w1, s1);
    }

    const float dm = -0.5f * LOG2E * (z0 * z0 + z1 * z1 + z2 * z2);
    // Packed 6-float layout: ws[6m..6m+5] = {z0, z1, z2, dm, w0s, w1s}.
    // 24B stride -> three 8B-aligned float2 stores per lane.
    float2* ws2 = (float2*)ws;
    ws2[3 * lane + 0] = make_float2(z0, z1);
    ws2[3 * lane + 1] = make_float2(z2, dm);
    ws2[3 * lane + 2] = make_float2(sf2 * w0v, sf2 * w1v);
}

// ---------------------------------------------------------------------------
// Kernel 2, R16: R14 base (2 pts/thread, 1954 blocks) + packed constants.
// A pair of m's = exactly 3 ds_read_b128 (96 reads/wave, -25% vs R14's 128)
// and the mm-loop (32 iters) at unroll 4 keeps 12 b128 in flight (deeper
// latency cover than R14's 8) at ~100-120 VGPR (below the 128 cliff).
//   q0 = {z0,z1,z2,dm}_even  q1 = {w0,w1 | z0,z1}_odd  q2 = {z2,dm,w0,w1}_odd
// ---------------------------------------------------------------------------
__global__ __launch_bounds__(256) void gp_forward(const float* __restrict__ X,
                                                  const float* __restrict__ ws,
                                                  const float* __restrict__ ell_p,
                                                  float* __restrict__ out, int n) {
    __shared__ float4 P[96];    // 32 m-pairs x 3 float4
    for (int i = threadIdx.x; i < 96; i += 256)
        P[i] = ((const float4*)ws)[i];
    const float inv_ell = 1.0f / ell_p[0];
    __syncthreads();

    const int t  = blockIdx.x * 256 + threadIdx.x;  // global thread id
    const int i0 = 2 * t;                            // first of 2 points

    // Load 6 contiguous floats (2 points x 3 dims) as 3 aligned float2.
    float p00, p01, p02, p10, p11, p12;
    if (i0 + 1 < n) {
        const float2* X2 = (const float2*)X;
        float2 xa = X2[3 * t + 0];
        float2 xb = X2[3 * t + 1];
        float2 xc = X2[3 * t + 2];
        p00 = xa.x; p01 = xa.y; p02 = xb.x;
        p10 = xb.y; p11 = xc.x; p12 = xc.y;
    } else if (i0 < n) {
        p00 = X[3 * i0 + 0]; p01 = X[3 * i0 + 1]; p02 = X[3 * i0 + 2];
        p10 = p00; p11 = p01; p12 = p02;
    } else {
        p00 = p01 = p02 = p10 = p11 = p12 = 0.0f;
    }

    float xt0[2], xt1[2], xt2[2], c[2];
    {
        float xs0 = p00 * inv_ell, xs1 = p01 * inv_ell, xs2 = p02 * inv_ell;
        c[0]  = -0.5f * LOG2E * (xs0 * xs0 + xs1 * xs1 + xs2 * xs2);
        xt0[0] = xs0 * LOG2E; xt1[0] = xs1 * LOG2E; xt2[0] = xs2 * LOG2E;
        xs0 = p10 * inv_ell; xs1 = p11 * inv_ell; xs2 = p12 * inv_ell;
        c[1]  = -0.5f * LOG2E * (xs0 * xs0 + xs1 * xs1 + xs2 * xs2);
        xt0[1] = xs0 * LOG2E; xt1[1] = xs1 * LOG2E; xt2[1] = xs2 * LOG2E;
    }

    float acc0[2] = {0.f, 0.f};
    float acc1[2] = {0.f, 0.f};

#pragma unroll 4
    for (int mm = 0; mm < 32; ++mm) {       // one m-PAIR per iteration
        const float4 q0 = P[3 * mm + 0];    // z0e z1e z2e dme
        const float4 q1 = P[3 * mm + 1];    // w0e w1e z0o z1o
        const float4 q2 = P[3 * mm + 2];    // z2o dmo w0o w1o
#pragma unroll
        for (int p = 0; p < 2; ++p) {
            float ae = fmaf(xt0[p], q0.x,
                       fmaf(xt1[p], q0.y,
                       fmaf(xt2[p], q0.z, c[p] + q0.w)));
            float ee = EXP2F(ae);
            acc0[p] = fmaf(ee, q1.x, acc0[p]);
            acc1[p] = fmaf(ee, q1.y, acc1[p]);

            float ao = fmaf(xt0[p], q1.z,
                       fmaf(xt1[p], q1.w,
                       fmaf(xt2[p], q2.x, c[p] + q2.y)));
            float eo = EXP2F(ao);
            acc0[p] = fmaf(eo, q2.z, acc0[p]);
            acc1[p] = fmaf(eo, q2.w, acc1[p]);
        }
    }

    if (i0 + 1 < n) {
        ((float4*)out)[t] = make_float4(acc0[0], acc1[0], acc0[1], acc1[1]);
    } else if (i0 < n) {
        ((float2*)out)[i0] = make_float2(acc0[0], acc1[0]);
    }
}

extern "C" void kernel_launch(void* const* d_in, const int* in_sizes, int n_in,
                              void* d_out, int out_size, void* d_ws, size_t ws_size,
                              hipStream_t stream) {
    // setup_inputs order: t, X, Z, U, sf, ell
    const float* X    = (const float*)d_in[1];
    const float* Z    = (const float*)d_in[2];
    const float* U    = (const float*)d_in[3];
    const float* sf   = (const float*)d_in[4];
    const float* ell  = (const float*)d_in[5];
    float* out = (float*)d_out;
    float* ws  = (float*)d_ws;
    const int N = in_sizes[1] / 3;

    gp_precompute<<<1, 64, 0, stream>>>(Z, U, sf, ell, ws);

    const int PTS_PER_BLOCK = 256 * 2;      // 2 points per thread
    const int blocks = (N + PTS_PER_BLOCK - 1) / PTS_PER_BLOCK;
    gp_forward<<<blocks, 256, 0, stream>>>(X, ws, ell, out, N);
}

// Round 17
// 38.838 us; speedup vs baseline: 1.1641x; 1.1293x over previous
//
#include <hip/hip_runtime.h>
#include <hip/hip_bf16.h>
#include <utility>

#define LOG2E 1.4426950408889634f

#if __has_builtin(__builtin_amdgcn_exp2f)
#define EXP2F(x) __builtin_amdgcn_exp2f(x)
#else
#define EXP2F(x) exp2f(x)
#endif

#if __has_builtin(__builtin_amdgcn_rsqf)
#define RSQ(x) __builtin_amdgcn_rsqf(x)
#else
#define RSQ(x) (1.0f / sqrtf(x))
#endif

// readlane: lane may be a literal OR a runtime-uniform (SGPR) value.
#define RDLANE(x, l) __int_as_float(__builtin_amdgcn_readlane(__float_as_int(x), (l)))

// ---------------------------------------------------------------------------
// Kernel 1, R17: readlane-hazard removal. R9's inner loops pair v_readlane
// with an immediately-dependent v_fma (SGPR write -> VALU read wait states,
// the pattern R12 measured as a loser in the forward). All bulk broadcasts
// now go through uniform LDS float4 reads instead:
//  - init: stage {z0,z1,z2} per lane, read back 1x b128 per j (was 3 readlane)
//  - chol step: lane writes lk to lkbuf; rank-1 update reads it as 16/8/4
//    uniform ds_read_b128 (4 lk per instr, VGPR dest, pipelined; was 64
//    readlane+fma hazard pairs)
// Only 1 readlane + 1 rsq per step remain. Single-wave barriers order the
// LDS write->read (cheap: one wave).
// ---------------------------------------------------------------------------
typedef float f16v __attribute__((ext_vector_type(16)));
struct Rows { f16v v0, v1, v2, v3; };

template<int J> __device__ __forceinline__ float getR(const Rows& r) {
    if constexpr (J < 16)      return r.v0[J];
    else if constexpr (J < 32) return r.v1[J - 16];
    else if constexpr (J < 48) return r.v2[J - 32];
    else                       return r.v3[J - 48];
}
template<int J> __device__ __forceinline__ void setR(Rows& r, float x) {
    if constexpr (J < 16)      r.v0[J] = x;
    else if constexpr (J < 32) r.v1[J - 16] = x;
    else if constexpr (J < 48) r.v2[J - 32] = x;
    else                       r.v3[J - 48] = x;
}

template<int LO, int W>
__device__ __forceinline__ float selR(const Rows& r, int k) {
    if constexpr (W == 1) {
        return getR<LO>(r);
    } else {
        float lo = selR<LO, W / 2>(r, k);
        float hi = selR<LO + W / 2, W / 2>(r, k);
        return (k & (W / 2)) ? hi : lo;   // uniform cond -> cndmask, CSE'd
    }
}

// Rank-1 update of one 4-column quad from a uniform float4 of lk values.
template<int Q>
__device__ __forceinline__ void upd_quad(Rows& r, float lk, const float4 lv) {
    setR<4 * Q + 0>(r, fmaf(-lk, lv.x, getR<4 * Q + 0>(r)));
    setR<4 * Q + 1>(r, fmaf(-lk, lv.y, getR<4 * Q + 1>(r)));
    setR<4 * Q + 2>(r, fmaf(-lk, lv.z, getR<4 * Q + 2>(r)));
    setR<4 * Q + 3>(r, fmaf(-lk, lv.w, getR<4 * Q + 3>(r)));
}
template<int QLO, int... Qs>
__device__ __forceinline__ void upd_quads(Rows& r, float lk, const float4* lkb4,
                                          std::integer_sequence<int, Qs...>) {
    (upd_quad<QLO + Qs>(r, lk, lkb4[QLO + Qs]), ...);
}

template<int... Js>
__device__ __forceinline__ void load_row(Rows& r, const float* Lrow,
                                         std::integer_sequence<int, Js...>) {
    (setR<Js>(r, Lrow[Js]), ...);
}

template<int KLO, int KHI, int ULO>
__device__ __forceinline__ void chol_phase(Rows& r, float* Lsh, float* lkbuf,
                                           int lane) {
    const float4* lkb4 = (const float4*)lkbuf;
#pragma clang loop unroll(disable)
    for (int k = KLO; k < KHI; ++k) {
        float rk  = selR<ULO, 64 - ULO>(r, k); // A[l][k] (valid l >= k)
        float dk  = RDLANE(rk, k);             // A[k][k], uniform
        float inv = RSQ(dk);                   // 1/L[k][k]
        float lk  = rk * inv;                  // L[l][k]
        float st  = (lane == k) ? inv : lk;    // diag slot stores reciprocal
        Lsh[lane * 65 + k] = st;               // sink column k (conflict-free)
        lkbuf[lane] = lk;                      // publish lk for the update
        __syncthreads();                       // 1-wave barrier: order w->r
        upd_quads<ULO / 4>(r, lk, lkb4,
                           std::make_integer_sequence<int, 16 - ULO / 4>{});
        __syncthreads();                       // reads done before next write
    }
}

__global__ __launch_bounds__(64, 1)
void gp_precompute(const float* __restrict__ Z, const float* __restrict__ U,
                   const float* __restrict__ sf_p, const float* __restrict__ ell_p,
                   float* __restrict__ ws) {
    __shared__ float Lsh[64 * 65];
    __shared__ float4 zbuf[64];
    __shared__ __align__(16) float lkbuf[64];
    const int lane = threadIdx.x;          // 64 threads = 1 wave
    const float sf  = sf_p[0];
    const float ell = ell_p[0];
    const float inv_ell = 1.0f / ell;
    const float sf2 = sf * sf;

    const float z0 = Z[lane * 3 + 0] * inv_ell;
    const float z1 = Z[lane * 3 + 1] * inv_ell;
    const float z2 = Z[lane * 3 + 2] * inv_ell;

    zbuf[lane] = make_float4(z0, z1, z2, 0.0f);
    __syncthreads();

    // Kzz row init: one uniform b128 per j (was 3 readlanes per j).
#pragma unroll 4
    for (int j = 0; j < 64; ++j) {
        float4 zj = zbuf[j];
        float dx = z0 - zj.x;
        float dy = z1 - zj.y;
        float dz = z2 - zj.z;
        float sq = dx * dx + dy * dy + dz * dz;
        Lsh[lane * 65 + j] = sf2 * EXP2F(-0.5f * LOG2E * sq);
    }
    __syncthreads();

    Rows r;
    load_row(r, &Lsh[lane * 65], std::make_integer_sequence<int, 64>{});

    chol_phase< 0, 32,  0>(r, Lsh, lkbuf, lane);
    chol_phase<32, 48, 32>(r, Lsh, lkbuf, lane);
    chol_phase<48, 64, 48>(r, Lsh, lkbuf, lane);
    __syncthreads();

    // Solve L^T W = U (column sweep, descending i).
    float s0 = U[lane * 2 + 0];
    float s1 = U[lane * 2 + 1];
    float w0v = 0.0f, w1v = 0.0f;
#pragma unroll 8
    for (int i = 63; i >= 0; --i) {
        float a   = Lsh[i * 65 + lane];    // L[i][lane]; lane i: 1/L[i][i]
        float rdi = RDLANE(a, i);          // 1/L[i][i]
        float w0  = RDLANE(s0, i) * rdi;   // W[i][0]
        float w1  = RDLANE(s1, i) * rdi;   // W[i][1]
        bool  me  = (lane == i);
        w0v = me ? w0 : w0v;
        w1v = me ? w1 : w1v;
        s0 = fmaf(-a, w0, s0);             // lanes >= i polluted after use
        s1 = fmaf(-a, w1, s1);
    }

    const float dm = -0.5f * LOG2E * (z0 * z0 + z1 * z1 + z2 * z2);
    float4* ws4 = (float4*)ws;
    ws4[lane * 2 + 0] = make_float4(z0, z1, z2, dm);
    ws4[lane * 2 + 1] = make_float4(sf2 * w0v, sf2 * w1v, 0.0f, 0.0f);
}

// ---------------------------------------------------------------------------
// Kernel 2 (byte-identical to R14, the best measured forward): LDS-broadcast
// m-loop, unroll 4, 2 pts/thread (1954 blocks), coalesced float2 X loads,
// single float4 store.
// ---------------------------------------------------------------------------
__global__ __launch_bounds__(256) void gp_forward(const float* __restrict__ X,
                                                  const float* __restrict__ ws,
                                                  const float* __restrict__ ell_p,
                                                  float* __restrict__ out, int n) {
    __shared__ float4 P[128];   // 64 structs of {zs0,zs1,zs2,dm | w0,w1,0,0}
    for (int i = threadIdx.x; i < 128; i += 256)
        P[i] = ((const float4*)ws)[i];
    const float inv_ell = 1.0f / ell_p[0];
    __syncthreads();

    const int t  = blockIdx.x * 256 + threadIdx.x;  // global thread id
    const int i0 = 2 * t;                            // first of 2 points

    // Load 6 contiguous floats (2 points x 3 dims) as 3 aligned float2.
    float p00, p01, p02, p10, p11, p12;
    if (i0 + 1 < n) {
        const float2* X2 = (const float2*)X;
        float2 xa = X2[3 * t + 0];
        float2 xb = X2[3 * t + 1];
        float2 xc = X2[3 * t + 2];
        p00 = xa.x; p01 = xa.y; p02 = xb.x;
        p10 = xb.y; p11 = xc.x; p12 = xc.y;
    } else if (i0 < n) {
        p00 = X[3 * i0 + 0]; p01 = X[3 * i0 + 1]; p02 = X[3 * i0 + 2];
        p10 = p00; p11 = p01; p12 = p02;
    } else {
        p00 = p01 = p02 = p10 = p11 = p12 = 0.0f;
    }

    float xt0[2], xt1[2], xt2[2], c[2];
    {
        float xs0 = p00 * inv_ell, xs1 = p01 * inv_ell, xs2 = p02 * inv_ell;
        c[0]  = -0.5f * LOG2E * (xs0 * xs0 + xs1 * xs1 + xs2 * xs2);
        xt0[0] = xs0 * LOG2E; xt1[0] = xs1 * LOG2E; xt2[0] = xs2 * LOG2E;
        xs0 = p10 * inv_ell; xs1 = p11 * inv_ell; xs2 = p12 * inv_ell;
        c[1]  = -0.5f * LOG2E * (xs0 * xs0 + xs1 * xs1 + xs2 * xs2);
        xt0[1] = xs0 * LOG2E; xt1[1] = xs1 * LOG2E; xt2[1] = xs2 * LOG2E;
    }

    float acc0[2] = {0.f, 0.f};
    float acc1[2] = {0.f, 0.f};

#pragma unroll 4
    for (int m = 0; m < 64; ++m) {          // register-lean: 4-iter window
        const float4 a = P[2 * m + 0];
        const float4 b = P[2 * m + 1];
#pragma unroll
        for (int p = 0; p < 2; ++p) {
            float arg = fmaf(xt0[p], a.x,
                        fmaf(xt1[p], a.y,
                        fmaf(xt2[p], a.z, c[p] + a.w)));
            float e = EXP2F(arg);
            acc0[p] = fmaf(e, b.x, acc0[p]);
            acc1[p] = fmaf(e, b.y, acc1[p]);
        }
    }

    if (i0 + 1 < n) {
        ((float4*)out)[t] = make_float4(acc0[0], acc1[0], acc0[1], acc1[1]);
    } else if (i0 < n) {
        ((float2*)out)[i0] = make_float2(acc0[0], acc1[0]);
    }
}

extern "C" void kernel_launch(void* const* d_in, const int* in_sizes, int n_in,
                              void* d_out, int out_size, void* d_ws, size_t ws_size,
                              hipStream_t stream) {
    // setup_inputs order: t, X, Z, U, sf, ell
    const float* X    = (const float*)d_in[1];
    const float* Z    = (const float*)d_in[2];
    const float* U    = (const float*)d_in[3];
    const float* sf   = (const float*)d_in[4];
    const float* ell  = (const float*)d_in[5];
    float* out = (float*)d_out;
    float* ws  = (float*)d_ws;
    const int N = in_sizes[1] / 3;

    gp_precompute<<<1, 64, 0, stream>>>(Z, U, sf, ell, ws);

    const int PTS_PER_BLOCK = 256 * 2;      // 2 points per thread
    const int blocks = (N + PTS_PER_BLOCK - 1) / PTS_PER_BLOCK;
    gp_forward<<<blocks, 256, 0, stream>>>(X, ws, ell, out, N);
}